// Round 8
// baseline (33.969 us; speedup 1.0000x reference)
//
#include <hip/hip_runtime.h>

// out[b,l,t] = #points with ceil(dist(pcd[b,i], locs[l])) <= t+1, t=0..14
// ceil(d)<=t+1 (d non-integer) <=> trunc(d)<=t: f=min(trunc(sqrt(d2)),15),
// histogram h[f], cnt[t]=prefix(h)[t]. Bucket 15 = garbage sink (never read).
//
// R8 = R6 mapping + in-kernel SoA repack + packed 2xf32 math:
//   locs grid (16,16,8) z-fastest -> aligned 4-loc group shares (x,y).
//   Block = 4 consecutive locs x all 8192 points of one batch.
//   Per 1024-pt chunk: stage AoS->SoA into LDS (ds-pipe work, not VALU),
//   then each thread processes point PAIRS read as ds_read_b64 ->
//   adjacent-VGPR pairs feed v_pk_add/mul/fma_f32 (2 points per VALU op
//   for dx/dy/dz/d2). sqrt/cvt/bucket tail stays scalar per point.
//   Histogram: 4x u64 nibble acc (fold after 12/12/8 pts), bucket-15 sink
//   dropped at fold; staged LDS reduction epilogue (aliased over stage bufs).

#define BATCH 4
#define NPTS 8192
#define NLOC 2048
#define NT 15
#define CH 1024
#define NCHUNK (NPTS / CH)   // 8

typedef float v2f __attribute__((ext_vector_type(2)));

#if __has_builtin(__builtin_amdgcn_sqrtf)
#define FAST_SQRT(x) __builtin_amdgcn_sqrtf(x)
#else
#define FAST_SQRT(x) sqrtf(x)
#endif

struct StageBufs { float Xs[CH]; float Ys[CH]; float Zs[CH]; };      // 12 KB
struct EpiBufs {
    uint smem1[256][17];           // 17408 B
    uint s2lo[4][4][16];           // bytes 0,2 as u16 pair
    uint s2hi[4][4][16];           // bytes 1,3 as u16 pair
    uint hfull[4][16];
};
union LdsU { StageBufs s; EpiBufs e; };   // ~19.7 KB -> 8 blocks/CU

__global__ __launch_bounds__(256) void manual_feature_kernel(
    const float* __restrict__ pcd, const float* __restrict__ locs,
    float* __restrict__ out)
{
    __shared__ LdsU L;

    const int tid  = threadIdx.x;
    const int b    = blockIdx.x >> 9;     // 0..3
    const int lt   = blockIdx.x & 511;    // 0..511
    const int loc0 = lt * 4;              // 4 consecutive locs: same (x,y), z-col

    // block-uniform loc coords
    const float lx  = locs[loc0 * 3 + 0];
    const float ly  = locs[loc0 * 3 + 1];
    const v2f nlx = {-lx, -lx};
    const v2f nly = {-ly, -ly};
    v2f nlz[4];
#pragma unroll
    for (int j = 0; j < 4; ++j) {
        const float z = locs[(loc0 + j) * 3 + 2];
        nlz[j] = (v2f){-z, -z};
    }

    // h2[loc][w]: byte-packed counts. w0: buckets 0,2,4,6  w1: 1,3,5,7
    // w2: 8,10,12,14  w3: 9,11,13,(15 dropped)
    uint h2[4][4];
#pragma unroll
    for (int j = 0; j < 4; ++j)
#pragma unroll
        for (int w = 0; w < 4; ++w) h2[j][w] = 0u;

    unsigned long long acc0 = 0ull, acc1 = 0ull, acc2 = 0ull, acc3 = 0ull;

#define FOLD()                                                       \
    {                                                                \
        unsigned long long* ap[4] = {&acc0, &acc1, &acc2, &acc3};    \
        _Pragma("unroll")                                            \
        for (int j = 0; j < 4; ++j) {                                \
            const uint lo = (uint)(*ap[j]);                          \
            const uint hi = (uint)(*ap[j] >> 32);                    \
            h2[j][0] += lo & 0x0F0F0F0Fu;                            \
            h2[j][1] += (lo >> 4) & 0x0F0F0F0Fu;                     \
            h2[j][2] += hi & 0x0F0F0F0Fu;                            \
            h2[j][3] += (hi >> 4) & 0x000F0F0Fu; /* drop bucket 15 */\
            *ap[j] = 0ull;                                           \
        }                                                            \
    }

    // float4 base of this batch; chunk c starts at float4 index c*768
    const float4* P4 = reinterpret_cast<const float4*>(pcd) + (size_t)b * 6144;

    for (int c = 0; c < NCHUNK; ++c) {
        // ---- stage chunk c: AoS -> SoA (4 points per thread) ----
        {
            const float4 f0 = P4[c * 768 + 3 * tid + 0];
            const float4 f1 = P4[c * 768 + 3 * tid + 1];
            const float4 f2 = P4[c * 768 + 3 * tid + 2];
            const int p = 4 * tid;
            L.s.Xs[p + 0] = f0.x; L.s.Xs[p + 1] = f0.w;
            L.s.Xs[p + 2] = f1.z; L.s.Xs[p + 3] = f2.y;
            L.s.Ys[p + 0] = f0.y; L.s.Ys[p + 1] = f1.x;
            L.s.Ys[p + 2] = f1.w; L.s.Ys[p + 3] = f2.z;
            L.s.Zs[p + 0] = f0.z; L.s.Zs[p + 1] = f1.y;
            L.s.Zs[p + 2] = f2.x; L.s.Zs[p + 3] = f2.w;
        }
        __syncthreads();

        // ---- compute: 2 pair-iters (4 points) per thread ----
#pragma unroll
        for (int it = 0; it < 2; ++it) {
            const int pi = it * 256 + tid;          // pair index in chunk
            const v2f x01 = *reinterpret_cast<const v2f*>(&L.s.Xs[2 * pi]);
            const v2f y01 = *reinterpret_cast<const v2f*>(&L.s.Ys[2 * pi]);
            const v2f z01 = *reinterpret_cast<const v2f*>(&L.s.Zs[2 * pi]);

            const v2f dx = x01 + nlx;
            const v2f dy = y01 + nly;
            v2f dxy = dx * dx;
            dxy = dy * dy + dxy;                    // pk_fma

#define DO_LOC(A, J)                                                 \
            {                                                        \
                const v2f dz = z01 + nlz[J];                         \
                const v2f d2 = dz * dz + dxy;      /* pk_fma */      \
                uint fa = (uint)FAST_SQRT(d2.x);                     \
                uint fb = (uint)FAST_SQRT(d2.y);                     \
                fa = fa < 15u ? fa : 15u;                            \
                fb = fb < 15u ? fb : 15u;                            \
                A = (1ull << (fa << 2)) + A;                         \
                A = (1ull << (fb << 2)) + A;                         \
            }
            DO_LOC(acc0, 0)
            DO_LOC(acc1, 1)
            DO_LOC(acc2, 2)
            DO_LOC(acc3, 3)
#undef DO_LOC
        }
        // fold after 12, 24, 32 points (nibble capacity 15 per period)
        if (c == 2 || c == 5 || c == 7) FOLD()
        __syncthreads();   // protect stage bufs (and epilogue aliasing)
    }
#undef FOLD

    // ---- staged reduction over the 256 threads (aliased LDS) ---------------
#pragma unroll
    for (int j = 0; j < 4; ++j)
#pragma unroll
        for (int w = 0; w < 4; ++w) L.e.smem1[tid][j * 4 + w] = h2[j][w];
    __syncthreads();

    // Stage 2: (loc,w,chunk) sums 16 threads, bytes split into u16 pairs.
    // capacity: 16 threads x <=32 = 512 < 65536.
    {
        const int loc = tid >> 6, w = (tid >> 4) & 3, ch = tid & 15;
        uint alo = 0u, ahi = 0u;
#pragma unroll
        for (int it = 0; it < 16; ++it) {
            const uint v = L.e.smem1[ch * 16 + it][loc * 4 + w];
            alo += v & 0x00FF00FFu;
            ahi += (v >> 8) & 0x00FF00FFu;
        }
        L.e.s2lo[loc][w][ch] = alo;
        L.e.s2hi[loc][w][ch] = ahi;
    }
    __syncthreads();

    // Stage 3a: (loc,bucket) sums the 16 chunks -> full u32 count.
    if (tid < 64) {
        const int loc = tid >> 4, bkt = tid & 15;
        const int w  = (bkt & 1) + ((bkt >> 3) << 1);
        const int by = (bkt >> 1) & 3;
        const uint* src = (by & 1) ? &L.e.s2hi[loc][w][0] : &L.e.s2lo[loc][w][0];
        const int sh = (by >> 1) * 16;
        uint s = 0u;
#pragma unroll
        for (int ch = 0; ch < 16; ++ch) s += (src[ch] >> sh) & 0xFFFFu;
        L.e.hfull[loc][bkt] = s;
    }
    __syncthreads();

    // Stage 3b: prefix over buckets; one writer per output element.
    if (tid < 60) {
        const int loc = tid / 15, t = tid - loc * 15;
        uint s = 0u;
#pragma unroll
        for (int bkt = 0; bkt < NT; ++bkt) s += (bkt <= t) ? L.e.hfull[loc][bkt] : 0u;
        out[((size_t)b * NLOC + (size_t)(loc0 + loc)) * NT + t] = (float)s;
    }
}

extern "C" void kernel_launch(void* const* d_in, const int* in_sizes, int n_in,
                              void* d_out, int out_size, void* d_ws, size_t ws_size,
                              hipStream_t stream) {
    const float* pcd  = (const float*)d_in[0];
    const float* locs = (const float*)d_in[1];
    float* out = (float*)d_out;
    manual_feature_kernel<<<dim3(BATCH * (NLOC / 4)), dim3(256), 0, stream>>>(
        pcd, locs, out);
}

// Round 9
// 25.727 us; speedup vs baseline: 1.3203x; 1.3203x over previous
//
#include <hip/hip_runtime.h>

// out[b,l,t] = #points with ceil(dist(pcd[b,i], locs[l])) <= t+1, t=0..14
// ceil(d)<=t+1 (d non-integer) <=> trunc(d)<=t: f=min(trunc(sqrt(d2)),15),
// histogram h[f], cnt[t]=prefix(h)[t]. Bucket 15 = garbage sink (never read).
//
// R9 = R6 mapping + two register-only tweaks (no new barriers/launches):
//   (1) pk-f32 z-column math: the 4 locs of a block share (x,y) and differ
//       only in z -> dz/d2 for loc-pairs via v_pk_add/fma_f32 on splatted
//       pz/dxy2 (operands already in regs; unlike R8 no LDS repack needed).
//   (2) 4-point register prefetch: group g+1's loads issue before group g's
//       compute (double-buffer in regs, +12 VGPR) to break lockstep stalls.
//   Histogram: 4x u64 nibble acc, fold after 12/24/32 pts (capacity 15),
//   bucket-15 sink dropped at fold; staged LDS reduction epilogue (R6's).

#define BATCH 4
#define NPTS 8192
#define NLOC 2048
#define NT 15

typedef float v2f __attribute__((ext_vector_type(2)));

#if __has_builtin(__builtin_amdgcn_sqrtf)
#define FAST_SQRT(x) __builtin_amdgcn_sqrtf(x)
#else
#define FAST_SQRT(x) sqrtf(x)
#endif

struct f3 { float x, y, z; };

__global__ __launch_bounds__(256) void manual_feature_kernel(
    const float* __restrict__ pcd, const float* __restrict__ locs,
    float* __restrict__ out)
{
    const int tid  = threadIdx.x;
    const int b    = blockIdx.x >> 9;     // 0..3
    const int lt   = blockIdx.x & 511;    // 0..511
    const int loc0 = lt * 4;              // 4 consecutive locs: same (x,y), z-col

    // block-uniform -> scalar loads / SGPRs
    const float lx = locs[loc0 * 3 + 0];
    const float ly = locs[loc0 * 3 + 1];
    const v2f nlz01 = {-locs[loc0 * 3 + 2], -locs[loc0 * 3 + 5]};
    const v2f nlz23 = {-locs[loc0 * 3 + 8], -locs[loc0 * 3 + 11]};

    // h2[loc][w]: byte-packed counts. w0: buckets 0,2,4,6  w1: 1,3,5,7
    // w2: 8,10,12,14  w3: 9,11,13,(15 dropped)
    uint h2[4][4];
#pragma unroll
    for (int j = 0; j < 4; ++j)
#pragma unroll
        for (int w = 0; w < 4; ++w) h2[j][w] = 0u;

    const f3* P = reinterpret_cast<const f3*>(pcd + (size_t)b * NPTS * 3);

    unsigned long long acc0 = 0ull, acc1 = 0ull, acc2 = 0ull, acc3 = 0ull;

#define FOLD()                                                       \
    {                                                                \
        unsigned long long* ap[4] = {&acc0, &acc1, &acc2, &acc3};    \
        _Pragma("unroll")                                            \
        for (int j = 0; j < 4; ++j) {                                \
            const uint lo = (uint)(*ap[j]);                          \
            const uint hi = (uint)(*ap[j] >> 32);                    \
            h2[j][0] += lo & 0x0F0F0F0Fu;                            \
            h2[j][1] += (lo >> 4) & 0x0F0F0F0Fu;                     \
            h2[j][2] += hi & 0x0F0F0F0Fu;                            \
            h2[j][3] += (hi >> 4) & 0x000F0F0Fu; /* drop bucket 15 */\
            *ap[j] = 0ull;                                           \
        }                                                            \
    }

    f3 cur[4], nxt[4];
#pragma unroll
    for (int i = 0; i < 4; ++i) cur[i] = P[i * 256 + tid];

#pragma unroll
    for (int g = 0; g < 8; ++g) {          // 8 groups x 4 points = 32 pts
        if (g < 7) {
#pragma unroll
            for (int i = 0; i < 4; ++i)
                nxt[i] = P[((g + 1) * 4 + i) * 256 + tid];
        }

#pragma unroll
        for (int i = 0; i < 4; ++i) {
            const float dx = cur[i].x - lx;
            const float dy = cur[i].y - ly;
            const float dxy2 = dy * dy + dx * dx;      // fma
            const v2f pz2   = {cur[i].z, cur[i].z};
            const v2f dxy22 = {dxy2, dxy2};

            const v2f dz01 = pz2 + nlz01;              // v_pk_add_f32
            const v2f dz23 = pz2 + nlz23;
            const v2f d201 = dz01 * dz01 + dxy22;      // v_pk_fma_f32
            const v2f d223 = dz23 * dz23 + dxy22;

#define DO_LOC(A, D2)                                                \
            {                                                        \
                const float d = FAST_SQRT(D2);                       \
                uint f = (uint)d;                                    \
                f = f < 15u ? f : 15u;                               \
                A = (1ull << (f << 2)) + A;                          \
            }
            DO_LOC(acc0, d201.x)
            DO_LOC(acc1, d201.y)
            DO_LOC(acc2, d223.x)
            DO_LOC(acc3, d223.y)
#undef DO_LOC
        }
#pragma unroll
        for (int i = 0; i < 4; ++i) cur[i] = nxt[i];
        // fold after 12, 24, 32 points (nibble capacity 15 per period)
        if (g == 2 || g == 5 || g == 7) FOLD()
    }
#undef FOLD

    // ---- staged reduction over the 256 threads -----------------------------
    __shared__ uint smem1[256][17];   // [thread][loc*4+w], odd stride
#pragma unroll
    for (int j = 0; j < 4; ++j)
#pragma unroll
        for (int w = 0; w < 4; ++w) smem1[tid][j * 4 + w] = h2[j][w];
    __syncthreads();

    // Stage 2: (loc,w,chunk) sums 16 threads, bytes split into u16 pairs.
    // capacity: 16 threads x <=32 = 512 < 65536.
    __shared__ uint s2lo[4][4][16];   // bytes 0(lo16),2(hi16)
    __shared__ uint s2hi[4][4][16];   // bytes 1(lo16),3(hi16)
    {
        const int loc = tid >> 6, w = (tid >> 4) & 3, ch = tid & 15;
        uint alo = 0u, ahi = 0u;
#pragma unroll
        for (int it = 0; it < 16; ++it) {
            const uint v = smem1[ch * 16 + it][loc * 4 + w];
            alo += v & 0x00FF00FFu;
            ahi += (v >> 8) & 0x00FF00FFu;
        }
        s2lo[loc][w][ch] = alo;
        s2hi[loc][w][ch] = ahi;
    }
    __syncthreads();

    // Stage 3a: (loc,bucket) sums the 16 chunks -> full u32 count.
    __shared__ uint hfull[4][16];
    if (tid < 64) {
        const int loc = tid >> 4, bkt = tid & 15;
        const int w  = (bkt & 1) + ((bkt >> 3) << 1);
        const int by = (bkt >> 1) & 3;
        const uint* src = (by & 1) ? &s2hi[loc][w][0] : &s2lo[loc][w][0];
        const int sh = (by >> 1) * 16;
        uint s = 0u;
#pragma unroll
        for (int ch = 0; ch < 16; ++ch) s += (src[ch] >> sh) & 0xFFFFu;
        hfull[loc][bkt] = s;
    }
    __syncthreads();

    // Stage 3b: prefix over buckets; one writer per output element.
    if (tid < 60) {
        const int loc = tid / 15, t = tid - loc * 15;
        uint s = 0u;
#pragma unroll
        for (int bkt = 0; bkt < NT; ++bkt) s += (bkt <= t) ? hfull[loc][bkt] : 0u;
        out[((size_t)b * NLOC + (size_t)(loc0 + loc)) * NT + t] = (float)s;
    }
}

extern "C" void kernel_launch(void* const* d_in, const int* in_sizes, int n_in,
                              void* d_out, int out_size, void* d_ws, size_t ws_size,
                              hipStream_t stream) {
    const float* pcd  = (const float*)d_in[0];
    const float* locs = (const float*)d_in[1];
    float* out = (float*)d_out;
    manual_feature_kernel<<<dim3(BATCH * (NLOC / 4)), dim3(256), 0, stream>>>(
        pcd, locs, out);
}

// Round 10
// 25.545 us; speedup vs baseline: 1.3298x; 1.0071x over previous
//
#include <hip/hip_runtime.h>

// out[b,l,t] = #points with ceil(dist(pcd[b,i], locs[l])) <= t+1, t=0..14
// ceil(d)<=t+1 (d non-integer) <=> trunc(d)<=t: f=min(trunc(sqrt(d2)),15),
// histogram h[f], cnt[t]=prefix(h)[t]. Bucket 15 = garbage sink (never read).
//
// R10: locs grid is (16,16,8) z-fastest -> aligned groups of EIGHT locs
// share (x,y) (R6-R9 only used 4). Block = 8 consecutive locs (one full
// z-column) x all 8192 points of one batch; grid = 4*256 = 1024 blocks.
//   - dx/dy/dxy2 + point load + addressing amortized over 8 pairs (was 4)
//   - VMEM/L2 traffic halves (each batch re-read by 256 blocks, not 512)
//   - dz/d2 via v_pk_add/fma_f32 on loc-pairs (4 pk ops each per point)
//   - 8x u64 nibble accs, fold after 12/24/32 pts (capacity 15/nibble),
//     bucket-15 sink dropped at fold; ~85 VGPR -> 4 waves/SIMD = grid cap.
//   - staged LDS reduction epilogue extended to 8 locs (36 KB, 4 blk/CU).

#define BATCH 4
#define NPTS 8192
#define NLOC 2048
#define NT 15

typedef float v2f __attribute__((ext_vector_type(2)));

#if __has_builtin(__builtin_amdgcn_sqrtf)
#define FAST_SQRT(x) __builtin_amdgcn_sqrtf(x)
#else
#define FAST_SQRT(x) sqrtf(x)
#endif

struct f3 { float x, y, z; };

__global__ __launch_bounds__(256) void manual_feature_kernel(
    const float* __restrict__ pcd, const float* __restrict__ locs,
    float* __restrict__ out)
{
    const int tid  = threadIdx.x;
    const int b    = blockIdx.x >> 8;     // 0..3
    const int lt   = blockIdx.x & 255;    // 0..255
    const int loc0 = lt * 8;              // 8 consecutive locs: one z-column

    // block-uniform -> scalar loads / SGPRs
    const float lx = locs[loc0 * 3 + 0];
    const float ly = locs[loc0 * 3 + 1];
    const v2f nlz01 = {-locs[loc0 * 3 + 2],  -locs[loc0 * 3 + 5]};
    const v2f nlz23 = {-locs[loc0 * 3 + 8],  -locs[loc0 * 3 + 11]};
    const v2f nlz45 = {-locs[loc0 * 3 + 14], -locs[loc0 * 3 + 17]};
    const v2f nlz67 = {-locs[loc0 * 3 + 20], -locs[loc0 * 3 + 23]};

    // h2[loc][w]: byte-packed counts. w0: buckets 0,2,4,6  w1: 1,3,5,7
    // w2: 8,10,12,14  w3: 9,11,13,(15 dropped)
    uint h2[8][4];
#pragma unroll
    for (int j = 0; j < 8; ++j)
#pragma unroll
        for (int w = 0; w < 4; ++w) h2[j][w] = 0u;

    const f3* P = reinterpret_cast<const f3*>(pcd + (size_t)b * NPTS * 3);

    unsigned long long acc0 = 0ull, acc1 = 0ull, acc2 = 0ull, acc3 = 0ull;
    unsigned long long acc4 = 0ull, acc5 = 0ull, acc6 = 0ull, acc7 = 0ull;

#define FOLD()                                                       \
    {                                                                \
        unsigned long long* ap[8] = {&acc0, &acc1, &acc2, &acc3,     \
                                     &acc4, &acc5, &acc6, &acc7};    \
        _Pragma("unroll")                                            \
        for (int j = 0; j < 8; ++j) {                                \
            const uint lo = (uint)(*ap[j]);                          \
            const uint hi = (uint)(*ap[j] >> 32);                    \
            h2[j][0] += lo & 0x0F0F0F0Fu;                            \
            h2[j][1] += (lo >> 4) & 0x0F0F0F0Fu;                     \
            h2[j][2] += hi & 0x0F0F0F0Fu;                            \
            h2[j][3] += (hi >> 4) & 0x000F0F0Fu; /* drop bucket 15 */\
            *ap[j] = 0ull;                                           \
        }                                                            \
    }

#pragma unroll
    for (int g = 0; g < 8; ++g) {          // 8 bursts x 4 points = 32 pts
        f3 pt[4];
#pragma unroll
        for (int i = 0; i < 4; ++i)
            pt[i] = P[(g * 4 + i) * 256 + tid];

#pragma unroll
        for (int i = 0; i < 4; ++i) {
            const float dx = pt[i].x - lx;
            const float dy = pt[i].y - ly;
            const float dxy2 = dy * dy + dx * dx;      // fma
            const v2f pz2   = {pt[i].z, pt[i].z};
            const v2f dxy22 = {dxy2, dxy2};

            const v2f dz01 = pz2 + nlz01;              // v_pk_add_f32
            const v2f dz23 = pz2 + nlz23;
            const v2f dz45 = pz2 + nlz45;
            const v2f dz67 = pz2 + nlz67;
            const v2f d201 = dz01 * dz01 + dxy22;      // v_pk_fma_f32
            const v2f d223 = dz23 * dz23 + dxy22;
            const v2f d245 = dz45 * dz45 + dxy22;
            const v2f d267 = dz67 * dz67 + dxy22;

#define DO_LOC(A, D2)                                                \
            {                                                        \
                const float d = FAST_SQRT(D2);                       \
                uint f = (uint)d;                                    \
                f = f < 15u ? f : 15u;                               \
                A = (1ull << (f << 2)) + A;  /* lshl_add_u64 */      \
            }
            DO_LOC(acc0, d201.x)
            DO_LOC(acc1, d201.y)
            DO_LOC(acc2, d223.x)
            DO_LOC(acc3, d223.y)
            DO_LOC(acc4, d245.x)
            DO_LOC(acc5, d245.y)
            DO_LOC(acc6, d267.x)
            DO_LOC(acc7, d267.y)
#undef DO_LOC
        }
        // fold after 12, 24, 32 points (nibble capacity 15 per period)
        if (g == 2 || g == 5 || g == 7) FOLD()
    }
#undef FOLD

    // ---- staged reduction over the 256 threads -----------------------------
    // smem1 row stride 33 (odd): write bank = (tid + j) mod 32 -> only the
    // free 2-way (lane vs lane+32) aliasing.
    __shared__ uint smem1[256][33];   // [thread][loc*4+w]
#pragma unroll
    for (int j = 0; j < 8; ++j)
#pragma unroll
        for (int w = 0; w < 4; ++w) smem1[tid][j * 4 + w] = h2[j][w];
    __syncthreads();

    // Stage 2: (loc,w,chunk) sums 32 threads, bytes split into u16 pairs.
    // capacity: 32 threads x <=32 = 1024 < 65536.
    __shared__ uint s2lo[8][4][8];    // bytes 0(lo16),2(hi16)
    __shared__ uint s2hi[8][4][8];    // bytes 1(lo16),3(hi16)
    {
        const int loc = tid >> 5, w = (tid >> 3) & 3, ch = tid & 7;
        uint alo = 0u, ahi = 0u;
#pragma unroll
        for (int it = 0; it < 32; ++it) {
            const uint v = smem1[ch * 32 + it][loc * 4 + w];
            alo += v & 0x00FF00FFu;
            ahi += (v >> 8) & 0x00FF00FFu;
        }
        s2lo[loc][w][ch] = alo;
        s2hi[loc][w][ch] = ahi;
    }
    __syncthreads();

    // Stage 3a: (loc,bucket) sums the 8 chunks -> full u32 count.
    __shared__ uint hfull[8][16];
    if (tid < 128) {
        const int loc = tid >> 4, bkt = tid & 15;
        const int w  = (bkt & 1) + ((bkt >> 3) << 1);
        const int by = (bkt >> 1) & 3;
        const uint* src = (by & 1) ? &s2hi[loc][w][0] : &s2lo[loc][w][0];
        const int sh = (by >> 1) * 16;
        uint s = 0u;
#pragma unroll
        for (int ch = 0; ch < 8; ++ch) s += (src[ch] >> sh) & 0xFFFFu;
        hfull[loc][bkt] = s;
    }
    __syncthreads();

    // Stage 3b: prefix over buckets; one writer per output element.
    if (tid < 120) {
        const int loc = tid / 15, t = tid - loc * 15;
        uint s = 0u;
#pragma unroll
        for (int bkt = 0; bkt < NT; ++bkt) s += (bkt <= t) ? hfull[loc][bkt] : 0u;
        out[((size_t)b * NLOC + (size_t)(loc0 + loc)) * NT + t] = (float)s;
    }
}

extern "C" void kernel_launch(void* const* d_in, const int* in_sizes, int n_in,
                              void* d_out, int out_size, void* d_ws, size_t ws_size,
                              hipStream_t stream) {
    const float* pcd  = (const float*)d_in[0];
    const float* locs = (const float*)d_in[1];
    float* out = (float*)d_out;
    manual_feature_kernel<<<dim3(BATCH * (NLOC / 8)), dim3(256), 0, stream>>>(
        pcd, locs, out);
}